// Round 4
// baseline (186.874 us; speedup 1.0000x reference)
//
#include <hip/hip_runtime.h>
#include <math.h>

#define TOPK 13
#define PI_F 3.14159265358979323846f
#define K1_CHUNKS 8      // chunks per gt-row (one wave each)
#define K1_CPB 4         // chunks (waves) per 256-thread block

typedef unsigned int u32;
typedef unsigned long long u64;

// monotone float -> uint mapping matching XLA total order
__device__ __forceinline__ u32 ford(float f) {
    u32 u = __float_as_uint(f);
    return (u & 0x80000000u) ? ~u : (u | 0x80000000u);
}
__device__ __forceinline__ float funord(u32 o) {
    u32 u = (o & 0x80000000u) ? (o & 0x7FFFFFFFu) : ~o;
    return __uint_as_float(u);
}

__device__ __forceinline__ float iou_fn(float4 g, float4 p) {
    float ltx = fmaxf(g.x, p.x), lty = fmaxf(g.y, p.y);
    float rbx = fminf(g.z, p.z), rby = fminf(g.w, p.w);
    float inter = fmaxf(rbx - ltx, 0.0f) * fmaxf(rby - lty, 0.0f);
    float a1 = fmaxf(g.z - g.x, 0.0f) * fmaxf(g.w - g.y, 0.0f);
    float a2 = fmaxf(p.z - p.x, 0.0f) * fmaxf(p.w - p.y, 0.0f);
    return inter / (((a1 + a2) - inter) + 1e-9f);
}

struct RowParams { float av, bar, offc, mx, mn; };

__device__ __forceinline__ RowParams row_params(float4 g) {
    float w = g.z - g.x, h = g.w - g.y;
    float ar = w / (h + 1e-5f);
    float ia = 1.0f / ar;
    RowParams rp;
    rp.av = ia / (2.0f - ia);
    rp.bar = 2.0f / ar;
    rp.offc = PI_F * (1.0f - 2.0f / (2.0f * ar));
    rp.mx = 0.5f + 0.5f * cosf(rp.offc);
    rp.mn = 0.5f + 0.5f * cosf(rp.bar * 90.0f / 180.0f * PI_F + rp.offc);
    return rp;
}

__device__ __forceinline__ float ang_measure(const RowParams& rp, float theta) {
    float cfv = 0.5f + 0.5f * cosf(rp.bar * theta / 180.0f * PI_F + rp.offc);
    float r = (cfv - rp.mn) / (rp.mx - rp.mn) * (1.0f - rp.av) + rp.av;
    return isnan(r) ? 0.0f : r;
}

// align in exact reference op order: (s**1 * iou**5) * ang**3, left-assoc
__device__ __forceinline__ float align_fn(float s, float iou, float r) {
    float iou2 = iou * iou;
    float iou5 = (iou2 * iou2) * iou;
    float r3 = (r * r) * r;
    return (s * iou5) * r3;
}

__device__ __forceinline__ void insert13(u64* arr, u64 key) {
    if (key > arr[TOPK - 1]) {
#pragma unroll
        for (int jj = 0; jj < TOPK; jj++) {
            u64 hi = arr[jj] > key ? arr[jj] : key;
            u64 lo = arr[jj] > key ? key : arr[jj];
            arr[jj] = hi;
            key = lo;
        }
    }
}

__global__ void k0_init(int* cnt, int* assign1, u32* pam, u32* pov, int BA, int BN) {
    int t = blockIdx.x * blockDim.x + threadIdx.x;
    if (t < BA) { cnt[t] = 0; assign1[t] = -1; }
    if (t < BN) { pam[t] = 0x80000000u; pov[t] = 0x80000000u; } // ord(+0.0f)
}

// ---------------------------------------------------------------------------
// k1: one WAVE per (gt-row, chunk-of-anchors). Explicit 1-deep software
// pipeline: iteration k+1's streaming loads (pbox/pang/anc, clamped addrs,
// unconditional) AND the speculative scattered score load (inGt computable
// from the prefetched anchor point alone) are issued before consuming
// iteration k — breaking the ~880-cycle dependent chain measured in r0/r3.
// No LDS, no barriers. Each wave writes its chunk's sorted top-13 key list
// to workspace; k1m merges. Exact: union of chunk-top13s ⊇ row-top13.
// ---------------------------------------------------------------------------
__global__ __launch_bounds__(256)
void k1_topk(const float* __restrict__ scores, const float* __restrict__ pbox,
             const float* __restrict__ pang, const float* __restrict__ anc,
             const int* __restrict__ glab, const float* __restrict__ gbox,
             const float* __restrict__ gang, const float* __restrict__ mgt,
             u64* __restrict__ wslist,
             int bs, int A, int n, int C) {
    int j = blockIdx.x;
    // XCD clustering: blocks of the same batch land on the same XCD (j % 8 == b % 8)
    int b = j % bs;
    int r2 = j / bs;
    int i = r2 % n;
    int cg = r2 / n;                 // chunk group (0..K1_CHUNKS/K1_CPB-1)
    int bi = b * n + i;
    int tid = threadIdx.x;
    int lane = tid & 63, wv = tid >> 6;
    int chunk = cg * K1_CPB + wv;

    if (!(mgt[bi] > 0.0f)) return;   // masked row contributes nothing

    float4 g = ((const float4*)gbox)[bi];
    int lab = glab[bi];
    float ga = gang[bi];
    RowParams rp = row_params(g);

    const float4* pb = ((const float4*)pbox) + (size_t)b * A;
    const float* pa = pang + (size_t)b * A;
    const float2* ac = (const float2*)anc;
    const float* sc = scores + (size_t)b * A * C + lab;

    int CS = (A + K1_CHUNKS - 1) / K1_CHUNKS;
    int start = chunk * CS;
    int end = min(start + CS, A);
    int clampA = end - 1;

    u64 arr[TOPK];
#pragma unroll
    for (int jj = 0; jj < TOPK; jj++) arr[jj] = 0ull;
    u64 zk0 = 0ull, zk1 = 0ull;  // thread's two lowest-index exact-+0 candidates

    // prologue: stage iteration 0
    int a = start + lane;
    int ca = min(a, clampA);
    float4 p = pb[ca];
    float pav = pa[ca];
    float2 apt = ac[ca];
    float mnv = fminf(fminf(apt.x - g.x, apt.y - g.y), fminf(g.z - apt.x, g.w - apt.y));
    bool inG = (mnv > 1e-9f) && (a < end);
    float s = 0.0f;
    if (inG) s = sc[(size_t)ca * C];   // speculative scatter prefetch

    // Exactness of the conditional-r path (reference v = align*in_gts,
    // align = (s*iou^5)*r^3, s>=0, iou>=0, r finite after NaN-replace):
    //  - !inGt or iou==0  -> v = +/-0 with sign(r); selectable only if +0.
    //  - inGt && iou>0    -> r>0: v = align (insert if >0, else +0 cand);
    //                       r==0: +0 cand; r<0: v<0 never selectable.
    //  sign(r) is only consumed while zk1 unset; cosf skipped afterwards.
    int nit = (end - start + 63) >> 6;
    for (int it = 0; it < nit; ++it) {
        // stage iteration it+1 (clamped, unconditional -> pipelineable)
        int an = a + 64;
        int can = min(an, clampA);
        float4 p2 = pb[can];
        float pav2 = pa[can];
        float2 apt2 = ac[can];
        float mnv2 = fminf(fminf(apt2.x - g.x, apt2.y - g.y),
                           fminf(g.z - apt2.x, g.w - apt2.y));
        bool inG2 = (mnv2 > 1e-9f) && (an < end);
        float s2 = 0.0f;
        if (inG2) s2 = sc[(size_t)can * C];

        // consume iteration it (values already resident)
        float iou = iou_fn(g, p);
        bool needAlign = inG && (iou > 0.0f);
        bool valid = a < end;
        if (needAlign || (zk1 == 0ull && valid)) {
            float th = fabsf(ga - pav);
            float r = ang_measure(rp, th);
            bool zeroCand;
            if (needAlign && r > 0.0f) {
                float v = align_fn(s, iou, r);
                if (v > 0.0f) {
                    zeroCand = false;
                    insert13(arr, ((u64)ford(v) << 32) | (u64)(0xFFFFFFFFu - (u32)a));
                } else {
                    zeroCand = true;  // s==0 or iou^5 underflow -> v == +0 exactly
                }
            } else {
                zeroCand = (r >= 0.0f);  // v == sign(r)*0; only +0 is selectable
            }
            if (zeroCand) {
                u64 kz = (0x80000000ull << 32) | (u64)(0xFFFFFFFFu - (u32)a);
                if (zk0 == 0ull) zk0 = kz;
                else if (zk1 == 0ull) zk1 = kz;
            }
        }
        a = an; p = p2; pav = pav2; mnv = mnv2; inG = inG2; s = s2;
    }
    insert13(arr, zk0);   // no-op when 0
    insert13(arr, zk1);

    // per-wave top-13 extraction -> workspace (13 wave-max rounds, no barriers;
    // keys unique since each anchor visited by exactly one thread, 0 = empty)
    u64* dst = wslist + ((size_t)bi * K1_CHUNKS + chunk) * TOPK;
    for (int round = 0; round < TOPK; round++) {
        u64 m = arr[0];
#pragma unroll
        for (int st = 32; st > 0; st >>= 1) {
            u64 o = __shfl_xor(m, st, 64);
            if (o > m) m = o;
        }
        if (lane == 0) dst[round] = m;   // write zeros too (k1m skips them)
        if (arr[0] == m && m != 0ull) {  // unique winner pops its head
#pragma unroll
            for (int jj = 0; jj < TOPK - 1; jj++) arr[jj] = arr[jj + 1];
            arr[TOPK - 1] = 0ull;
        }
    }
}

// ---------------------------------------------------------------------------
// k1m: one wave per gt-row. Merge the K1_CHUNKS sorted 13-lists (104 keys)
// and fire the cnt/assign1 atomics for the row top-13 (same structure as the
// proven round-1 phase-2 merge).
// ---------------------------------------------------------------------------
__global__ __launch_bounds__(64)
void k1m_merge(const float* __restrict__ anc, const float* __restrict__ gbox,
               const float* __restrict__ mgt, const u64* __restrict__ wslist,
               int* __restrict__ cnt, int* __restrict__ assign1,
               int bs, int A, int n) {
    int j = blockIdx.x;
    int b = j % bs;                  // XCD spread
    int i = j / bs;
    int bi = b * n + i;
    if (!(mgt[bi] > 0.0f)) return;
    int lane = threadIdx.x;

    const int NK = K1_CHUNKS * TOPK; // 104
    const u64* src = wslist + (size_t)bi * NK;
    u64 ka = src[lane];
    u64 kb = (lane + 64 < NK) ? src[lane + 64] : 0ull;

    float4 g = ((const float4*)gbox)[bi];
    const float2* ac = (const float2*)anc;

    for (int round = 0; round < TOPK; round++) {
        u64 m = ka > kb ? ka : kb;
#pragma unroll
        for (int st = 32; st > 0; st >>= 1) {
            u64 o = __shfl_xor(m, st, 64);
            if (o > m) m = o;
        }
        if (m == 0ull) break;        // uniform across wave -> safe
        bool own = false;
        if (ka == m) { ka = 0ull; own = true; }
        else if (kb == m) { kb = 0ull; own = true; }
        if (own) {                   // keys unique -> exactly one owner lane
            int aa = (int)(0xFFFFFFFFu - (u32)(m & 0xFFFFFFFFull));
            float2 apt = ac[aa];
            float mnv = fminf(fminf(apt.x - g.x, apt.y - g.y),
                              fminf(g.z - apt.x, g.w - apt.y));
            if (mnv > 1e-9f) {       // mask_pos = mask_topk * in_gts * mask_gt
                atomicAdd(&cnt[(size_t)b * A + aa], 1);
                atomicMax(&assign1[(size_t)b * A + aa], i);
            }
        }
    }
}

__global__ __launch_bounds__(256)
void k2_resolve(const float* __restrict__ scores, const float* __restrict__ pbox,
                const float* __restrict__ pang, const int* __restrict__ glab,
                const float* __restrict__ gbox, const float* __restrict__ gang,
                const int* __restrict__ cnt, const int* __restrict__ assign1,
                int* __restrict__ assign, float* __restrict__ alignv,
                u32* __restrict__ pam, u32* __restrict__ pov,
                int bs, int A, int n, int C) {
    int t = blockIdx.x * blockDim.x + threadIdx.x;
    if (t >= bs * A) return;
    int b = t / A;
    int c = cnt[t];
    int asg = -1;
    float alv = 0.0f;
    if (c > 0) {
        float4 p = ((const float4*)pbox)[t];
        if (c == 1) {
            asg = assign1[t];
        } else {
            // reference: overlaps.argmax(1) over ALL gt rows, first-max tie-break
            float best = -1.0f;
            asg = 0;
            for (int i = 0; i < n; i++) {
                float4 gi = ((const float4*)gbox)[b * n + i];
                float io = iou_fn(gi, p);
                if (io > best) { best = io; asg = i; }
            }
        }
        float4 g = ((const float4*)gbox)[b * n + asg];
        RowParams rp = row_params(g);
        float iou = iou_fn(g, p);
        float th = fabsf(gang[b * n + asg] - pang[t]);
        float r = ang_measure(rp, th);
        float s = scores[(size_t)t * C + glab[b * n + asg]];
        alv = align_fn(s, iou, r);
        atomicMax(&pam[b * n + asg], ford(alv));
        atomicMax(&pov[b * n + asg], ford(iou));
    }
    assign[t] = asg;
    alignv[t] = alv;
}

__global__ __launch_bounds__(256)
void k3_out(const int* __restrict__ glab, const float* __restrict__ gbox,
            const float* __restrict__ gang, const int* __restrict__ assign,
            const float* __restrict__ alignv, const u32* __restrict__ pam,
            const u32* __restrict__ pov, float* __restrict__ out,
            int bs, int A, int n, int C) {
    __shared__ float s_nv[256];
    __shared__ int s_lf[256];
    int tid = threadIdx.x;
    int base = blockIdx.x * 256;
    int t = base + tid;
    int BA = bs * A;

    if (t < BA) {
        int b = t / A;
        int asg = assign[t];
        bool fg = asg >= 0;
        int tgt = fg ? asg : 0;  // argmax of all-zero column -> row 0
        int lb = glab[b * n + tgt];
        if (lb < 0) lb = 0;

        float* o_tlab = out;
        float* o_tbb = out + BA;
        float* o_tang = out + (size_t)BA * 5;
        float* o_fg = out + (size_t)BA * 6 + (size_t)BA * C;

        o_tlab[t] = (float)lb;
        ((float4*)o_tbb)[t] = ((const float4*)gbox)[b * n + tgt];
        o_tang[t] = gang[b * n + tgt];
        o_fg[t] = fg ? 1.0f : 0.0f;

        float nv = 0.0f;
        if (fg) {
            float pamv = funord(pam[b * n + asg]);
            float povv = funord(pov[b * n + asg]);
            float vv = (alignv[t] * povv) / (pamv + 1e-9f);
            nv = fmaxf(vv, 0.0f);  // 59 other rows contribute exactly 0 to the max
        }
        s_nv[tid] = nv;
        s_lf[tid] = fg ? lb : -1;
    } else {
        s_nv[tid] = 0.0f;
        s_lf[tid] = -1;
    }
    __syncthreads();

    // ts: coalesced float4 writes, (anchor, class-quad) with quad fastest
    int Q = C / 4;  // 20
    int nA = min(256, BA - base);
    if (nA <= 0) return;
    int total = nA * Q;
    float4* o_ts = (float4*)(out + (size_t)BA * 6) + (size_t)base * Q;
    for (int idx = tid; idx < total; idx += 256) {
        int tl = idx / Q;
        int q = idx - tl * Q;
        float nv = s_nv[tl];
        int lf = s_lf[tl];
        int cb = q * 4;
        float4 o;
        o.x = (lf == cb) ? nv : 0.0f;
        o.y = (lf == cb + 1) ? nv : 0.0f;
        o.z = (lf == cb + 2) ? nv : 0.0f;
        o.w = (lf == cb + 3) ? nv : 0.0f;
        o_ts[idx] = o;
    }
}

extern "C" void kernel_launch(void* const* d_in, const int* in_sizes, int n_in,
                              void* d_out, int out_size, void* d_ws, size_t ws_size,
                              hipStream_t stream) {
    const float* scores = (const float*)d_in[0];
    const float* pbox = (const float*)d_in[1];
    const float* pang = (const float*)d_in[2];
    const float* anc = (const float*)d_in[3];
    const int* glab = (const int*)d_in[4];
    const float* gbox = (const float*)d_in[5];
    const float* gang = (const float*)d_in[6];
    const float* mgt = (const float*)d_in[7];

    const int C = 80;
    int A = in_sizes[3] / 2;
    int bs = in_sizes[0] / (A * C);
    int n = in_sizes[4] / bs;
    int BA = bs * A;
    int BN = bs * n;

    char* ws = (char*)d_ws;
    u64* wslist = (u64*)ws;     ws += sizeof(u64) * (size_t)BN * K1_CHUNKS * TOPK;
    int* cnt = (int*)ws;        ws += sizeof(int) * (size_t)BA;
    int* assign1 = (int*)ws;    ws += sizeof(int) * (size_t)BA;
    int* assign = (int*)ws;     ws += sizeof(int) * (size_t)BA;
    float* alignv = (float*)ws; ws += sizeof(float) * (size_t)BA;
    u32* pam = (u32*)ws;        ws += sizeof(u32) * (size_t)BN;
    u32* pov = (u32*)ws;        ws += sizeof(u32) * (size_t)BN;

    k0_init<<<(BA + 255) / 256, 256, 0, stream>>>(cnt, assign1, pam, pov, BA, BN);
    k1_topk<<<BN * (K1_CHUNKS / K1_CPB), 256, 0, stream>>>(scores, pbox, pang, anc, glab,
                                                           gbox, gang, mgt, wslist,
                                                           bs, A, n, C);
    k1m_merge<<<BN, 64, 0, stream>>>(anc, gbox, mgt, wslist, cnt, assign1, bs, A, n);
    k2_resolve<<<(BA + 255) / 256, 256, 0, stream>>>(scores, pbox, pang, glab, gbox, gang,
                                                     cnt, assign1, assign, alignv, pam, pov,
                                                     bs, A, n, C);
    k3_out<<<(BA + 255) / 256, 256, 0, stream>>>(glab, gbox, gang, assign, alignv, pam, pov,
                                                 (float*)d_out, bs, A, n, C);
}

// Round 6
// 161.499 us; speedup vs baseline: 1.1571x; 1.1571x over previous
//
#include <hip/hip_runtime.h>
#include <math.h>

#define TOPK 13
#define PI_F 3.14159265358979323846f
#define K1_WAVES 4

typedef unsigned int u32;
typedef unsigned long long u64;

// monotone float -> uint mapping matching XLA total order
__device__ __forceinline__ u32 ford(float f) {
    u32 u = __float_as_uint(f);
    return (u & 0x80000000u) ? ~u : (u | 0x80000000u);
}
__device__ __forceinline__ float funord(u32 o) {
    u32 u = (o & 0x80000000u) ? (o & 0x7FFFFFFFu) : ~o;
    return __uint_as_float(u);
}

__device__ __forceinline__ float iou_fn(float4 g, float4 p) {
    float ltx = fmaxf(g.x, p.x), lty = fmaxf(g.y, p.y);
    float rbx = fminf(g.z, p.z), rby = fminf(g.w, p.w);
    float inter = fmaxf(rbx - ltx, 0.0f) * fmaxf(rby - lty, 0.0f);
    float a1 = fmaxf(g.z - g.x, 0.0f) * fmaxf(g.w - g.y, 0.0f);
    float a2 = fmaxf(p.z - p.x, 0.0f) * fmaxf(p.w - p.y, 0.0f);
    return inter / (((a1 + a2) - inter) + 1e-9f);
}

struct RowParams { float av, bar, offc, mx, mn; };

__device__ __forceinline__ RowParams row_params(float4 g) {
    float w = g.z - g.x, h = g.w - g.y;
    float ar = w / (h + 1e-5f);
    float ia = 1.0f / ar;
    RowParams rp;
    rp.av = ia / (2.0f - ia);
    rp.bar = 2.0f / ar;
    rp.offc = PI_F * (1.0f - 2.0f / (2.0f * ar));
    rp.mx = 0.5f + 0.5f * cosf(rp.offc);
    rp.mn = 0.5f + 0.5f * cosf(rp.bar * 90.0f / 180.0f * PI_F + rp.offc);
    return rp;
}

__device__ __forceinline__ float ang_measure(const RowParams& rp, float theta) {
    float cfv = 0.5f + 0.5f * cosf(rp.bar * theta / 180.0f * PI_F + rp.offc);
    float r = (cfv - rp.mn) / (rp.mx - rp.mn) * (1.0f - rp.av) + rp.av;
    return isnan(r) ? 0.0f : r;
}

// align in exact reference op order: (s**1 * iou**5) * ang**3, left-assoc
__device__ __forceinline__ float align_fn(float s, float iou, float r) {
    float iou2 = iou * iou;
    float iou5 = (iou2 * iou2) * iou;
    float r3 = (r * r) * r;
    return (s * iou5) * r3;
}

__device__ __forceinline__ void insert13(u64* arr, u64 key) {
    if (key > arr[TOPK - 1]) {
#pragma unroll
        for (int jj = 0; jj < TOPK; jj++) {
            u64 hi = arr[jj] > key ? arr[jj] : key;
            u64 lo = arr[jj] > key ? key : arr[jj];
            arr[jj] = hi;
            key = lo;
        }
    }
}

__global__ void k0_init(int* cnt, int* assign1, u32* pam, u32* pov, int BA, int BN) {
    int t = blockIdx.x * blockDim.x + threadIdx.x;
    if (t < BA) { cnt[t] = 0; assign1[t] = -1; }
    if (t < BN) { pam[t] = 0x80000000u; pov[t] = 0x80000000u; } // ord(+0.0f)
}

// ---------------------------------------------------------------------------
// k1: one block per (batch, gt-row), 4 waves. Explicit 1-deep software
// pipeline on the STREAMING loads only (pbox/pang/anc, clamped addresses,
// unconditional — r4 proved the mechanism; r4's regressions — chunk warm-up
// cosf x8 and speculative score prefetch — are omitted). The scattered score
// load stays on-demand in the rare path. Additionally hides the 43 MB ts
// zero-fill (one fire-and-forget float4 store per iteration) under the scan,
// so k3 only writes 3.8 MB + one scattered element per fg anchor.
// Classification logic byte-identical to the round-3 passing kernel.
// ---------------------------------------------------------------------------
__global__ __launch_bounds__(256)
void k1_topk(const float* __restrict__ scores, const float* __restrict__ pbox,
             const float* __restrict__ pang, const float* __restrict__ anc,
             const int* __restrict__ glab, const float* __restrict__ gbox,
             const float* __restrict__ gang, const float* __restrict__ mgt,
             int* __restrict__ cnt, int* __restrict__ assign1,
             float* __restrict__ out,
             int bs, int A, int n, int C) {
    int j = blockIdx.x;
    // XCD clustering: blocks of the same batch land on the same XCD (j % 8 == b % 8)
    int b = j % bs;
    int i = j / bs;
    int bi = b * n + i;
    int tid = threadIdx.x;
    int BA = bs * A;

    // ts zero-fill chunk for this block (hidden under the anchor scan)
    int nF4 = BA * (C / 4);
    int zCH = (nF4 + gridDim.x - 1) / gridDim.x;
    int zBeg = j * zCH + tid;
    int zEnd = min(j * zCH + zCH, nF4);
    float4* tsf4 = (float4*)(out + (size_t)BA * 6);
    const float4 z4 = make_float4(0.0f, 0.0f, 0.0f, 0.0f);

    float mg = mgt[bi];
    if (!(mg > 0.0f)) {
        // masked row contributes no candidates, but still owns its ts chunk
        for (; zBeg < zEnd; zBeg += 256) tsf4[zBeg] = z4;
        return;
    }

    float4 g = ((const float4*)gbox)[bi];
    int lab = glab[bi];
    float ga = gang[bi];
    RowParams rp = row_params(g);

    const float4* pb = ((const float4*)pbox) + (size_t)b * A;
    const float* pa = pang + (size_t)b * A;
    const float2* ac = (const float2*)anc;
    const float* sc = scores + (size_t)b * A * C + lab;

    u64 arr[TOPK];
#pragma unroll
    for (int jj = 0; jj < TOPK; jj++) arr[jj] = 0ull;
    u64 zkey = 0ull;  // thread's lowest-index exact-+0 candidate

    // prologue: stage iteration 0 (tid < 256 <= A, so a is valid)
    int a = tid;
    float4 p = pb[a];
    float pav = pa[a];
    float2 apt = ac[a];
    float mnv = fminf(fminf(apt.x - g.x, apt.y - g.y), fminf(g.z - apt.x, g.w - apt.y));

    // Exactness of the conditional-r path (reference v = align*in_gts,
    // align = (s*iou^5)*r^3, s>=0, iou>=0, r finite after NaN-replace):
    //  - !inGt or iou==0  -> v = +/-0 with sign(r); selectable only if +0.
    //  - inGt && iou>0    -> r>0: v = align (insert if >0, else +0 cand);
    //                       r==0: +0 cand; r<0: v<0 never selectable.
    //  sign(r) only consumed while zkey unset -> cosf skipped afterwards.
    int nit = (A + 255) >> 8;          // uniform trip count; tail guarded by `valid`
    int clampA = A - 1;
    for (int it = 0; it < nit; ++it) {
        // stage iteration it+1 (clamped, unconditional -> pipelineable)
        int an = a + 256;
        int can = min(an, clampA);
        float4 p2 = pb[can];
        float pav2 = pa[can];
        float2 apt2 = ac[can];
        // hidden zero-fill store (independent, fire-and-forget)
        if (zBeg < zEnd) { tsf4[zBeg] = z4; zBeg += 256; }
        float mnv2 = fminf(fminf(apt2.x - g.x, apt2.y - g.y),
                           fminf(g.z - apt2.x, g.w - apt2.y));

        // consume iteration it (operands already resident)
        bool valid = a < A;
        float iou = iou_fn(g, p);
        bool needAlign = (mnv > 1e-9f) && (iou > 0.0f) && valid;
        if (needAlign || (zkey == 0ull && valid)) {
            float th = fabsf(ga - pav);
            float r = ang_measure(rp, th);
            bool zeroCand;
            if (needAlign && r > 0.0f) {
                float s = sc[(size_t)a * C];   // scattered load, rare path only
                float v = align_fn(s, iou, r);
                if (v > 0.0f) {
                    zeroCand = false;
                    insert13(arr, ((u64)ford(v) << 32) | (u64)(0xFFFFFFFFu - (u32)a));
                } else {
                    zeroCand = true;  // s==0 or iou^5 underflow -> v == +0 exactly
                }
            } else {
                zeroCand = (r >= 0.0f);  // v == sign(r)*0; only +0 is selectable
            }
            if (zeroCand && zkey == 0ull) {
                zkey = (0x80000000ull << 32) | (u64)(0xFFFFFFFFu - (u32)a);
            }
        }
        a = an; p = p2; pav = pav2; mnv = mnv2;
    }
    for (; zBeg < zEnd; zBeg += 256) tsf4[zBeg] = z4;  // drain (normally no-op)
    // merge the single zero candidate (sufficient per thread: the 13
    // lowest-index zero candidates land on distinct threads at stride 256)
    insert13(arr, zkey);

    // Phase 1: per-wave top-13 (no barriers; keys unique, 0 = empty).
    __shared__ u64 wtop[K1_WAVES * TOPK];
    int lane = tid & 63, wv = tid >> 6;
    for (int round = 0; round < TOPK; round++) {
        u64 m = arr[0];
#pragma unroll
        for (int st = 32; st > 0; st >>= 1) {
            u64 o = __shfl_xor(m, st, 64);
            if (o > m) m = o;
        }
        if (lane == 0) wtop[wv * TOPK + round] = m;
        if (arr[0] == m && m != 0ull) {  // unique winner pops its head
#pragma unroll
            for (int jj = 0; jj < TOPK - 1; jj++) arr[jj] = arr[jj + 1];
            arr[TOPK - 1] = 0ull;
        }
    }
    __syncthreads();

    // Phase 2: wave 0 merges the 4 sorted 13-lists (52 keys, one per lane)
    // and fires the atomics for the block top-13.
    if (wv == 0) {
        const int NK = K1_WAVES * TOPK;  // 52
        u64 ka = (lane < NK) ? wtop[lane] : 0ull;
        for (int round = 0; round < TOPK; round++) {
            u64 m = ka;
#pragma unroll
            for (int st = 32; st > 0; st >>= 1) {
                u64 o = __shfl_xor(m, st, 64);
                if (o > m) m = o;
            }
            if (m == 0ull) break;        // uniform across wave 0 -> safe
            if (ka == m) {               // unique owner lane processes the winner
                ka = 0ull;
                int aa = (int)(0xFFFFFFFFu - (u32)(m & 0xFFFFFFFFull));
                float2 ap2 = ac[aa];
                float mnw = fminf(fminf(ap2.x - g.x, ap2.y - g.y),
                                  fminf(g.z - ap2.x, g.w - ap2.y));
                if (mnw > 1e-9f) {  // mask_pos = mask_topk * in_gts * mask_gt
                    atomicAdd(&cnt[(size_t)b * A + aa], 1);
                    atomicMax(&assign1[(size_t)b * A + aa], i);
                }
            }
        }
    }
}

__global__ __launch_bounds__(256)
void k2_resolve(const float* __restrict__ scores, const float* __restrict__ pbox,
                const float* __restrict__ pang, const int* __restrict__ glab,
                const float* __restrict__ gbox, const float* __restrict__ gang,
                const int* __restrict__ cnt, const int* __restrict__ assign1,
                int* __restrict__ assign, float* __restrict__ alignv,
                u32* __restrict__ pam, u32* __restrict__ pov,
                int bs, int A, int n, int C) {
    int t = blockIdx.x * blockDim.x + threadIdx.x;
    if (t >= bs * A) return;
    int b = t / A;
    int c = cnt[t];
    int asg = -1;
    float alv = 0.0f;
    if (c > 0) {
        float4 p = ((const float4*)pbox)[t];
        if (c == 1) {
            asg = assign1[t];
        } else {
            // reference: overlaps.argmax(1) over ALL gt rows, first-max tie-break
            float best = -1.0f;
            asg = 0;
            for (int i = 0; i < n; i++) {
                float4 gi = ((const float4*)gbox)[b * n + i];
                float io = iou_fn(gi, p);
                if (io > best) { best = io; asg = i; }
            }
        }
        float4 g = ((const float4*)gbox)[b * n + asg];
        RowParams rp = row_params(g);
        float iou = iou_fn(g, p);
        float th = fabsf(gang[b * n + asg] - pang[t]);
        float r = ang_measure(rp, th);
        float s = scores[(size_t)t * C + glab[b * n + asg]];
        alv = align_fn(s, iou, r);
        atomicMax(&pam[b * n + asg], ford(alv));
        atomicMax(&pov[b * n + asg], ford(iou));
    }
    assign[t] = asg;
    alignv[t] = alv;
}

// ---------------------------------------------------------------------------
// k3: outputs. ts zeros were pre-written by k1; only writes tlab/tbb/tang/fg
// (3.8 MB) plus ONE scattered ts element per fg anchor.
// ---------------------------------------------------------------------------
__global__ __launch_bounds__(256)
void k3_out(const int* __restrict__ glab, const float* __restrict__ gbox,
            const float* __restrict__ gang, const int* __restrict__ assign,
            const float* __restrict__ alignv, const u32* __restrict__ pam,
            const u32* __restrict__ pov, float* __restrict__ out,
            int bs, int A, int n, int C) {
    int t = blockIdx.x * blockDim.x + threadIdx.x;
    int BA = bs * A;
    if (t >= BA) return;
    int b = t / A;
    int asg = assign[t];
    bool fg = asg >= 0;
    int tgt = fg ? asg : 0;  // argmax of all-zero column -> row 0
    int lb = glab[b * n + tgt];
    if (lb < 0) lb = 0;

    out[t] = (float)lb;                                             // tlab
    ((float4*)(out + BA))[t] = ((const float4*)gbox)[b * n + tgt];  // tbb
    out[(size_t)BA * 5 + t] = gang[b * n + tgt];                    // tang
    out[(size_t)BA * 6 + (size_t)BA * C + t] = fg ? 1.0f : 0.0f;    // fg

    if (fg) {
        float pamv = funord(pam[b * n + asg]);
        float povv = funord(pov[b * n + asg]);
        float vv = (alignv[t] * povv) / (pamv + 1e-9f);
        // one_hot row: zeros pre-written by k1; single nonzero element.
        // (59 other gt rows contribute exactly 0 to the reference max.)
        out[(size_t)BA * 6 + (size_t)t * C + lb] = fmaxf(vv, 0.0f);
    }
}

extern "C" void kernel_launch(void* const* d_in, const int* in_sizes, int n_in,
                              void* d_out, int out_size, void* d_ws, size_t ws_size,
                              hipStream_t stream) {
    const float* scores = (const float*)d_in[0];
    const float* pbox = (const float*)d_in[1];
    const float* pang = (const float*)d_in[2];
    const float* anc = (const float*)d_in[3];
    const int* glab = (const int*)d_in[4];
    const float* gbox = (const float*)d_in[5];
    const float* gang = (const float*)d_in[6];
    const float* mgt = (const float*)d_in[7];

    const int C = 80;
    int A = in_sizes[3] / 2;
    int bs = in_sizes[0] / (A * C);
    int n = in_sizes[4] / bs;
    int BA = bs * A;
    int BN = bs * n;

    char* ws = (char*)d_ws;
    int* cnt = (int*)ws;        ws += sizeof(int) * (size_t)BA;
    int* assign1 = (int*)ws;    ws += sizeof(int) * (size_t)BA;
    int* assign = (int*)ws;     ws += sizeof(int) * (size_t)BA;
    float* alignv = (float*)ws; ws += sizeof(float) * (size_t)BA;
    u32* pam = (u32*)ws;        ws += sizeof(u32) * (size_t)BN;
    u32* pov = (u32*)ws;        ws += sizeof(u32) * (size_t)BN;

    k0_init<<<(BA + 255) / 256, 256, 0, stream>>>(cnt, assign1, pam, pov, BA, BN);
    k1_topk<<<BN, 256, 0, stream>>>(scores, pbox, pang, anc, glab, gbox, gang, mgt,
                                    cnt, assign1, (float*)d_out, bs, A, n, C);
    k2_resolve<<<(BA + 255) / 256, 256, 0, stream>>>(scores, pbox, pang, glab, gbox, gang,
                                                     cnt, assign1, assign, alignv, pam, pov,
                                                     bs, A, n, C);
    k3_out<<<(BA + 255) / 256, 256, 0, stream>>>(glab, gbox, gang, assign, alignv, pam, pov,
                                                 (float*)d_out, bs, A, n, C);
}